// Round 2
// baseline (202.073 us; speedup 1.0000x reference)
//
#include <hip/hip_runtime.h>
#include <hip/hip_bf16.h>
#include <math.h>

// Problem constants (CPUEfficientCausalAttention): B=2, S=2048, HIDDEN=1024, H=16, hd=64
#define HIDDEN 1024
#define HEADS 16
#define HDIM 64
#define BATCH 2
#define SEQ 2048
#define BHN (BATCH*HEADS)   // 32
#define MTOT (BATCH*SEQ)    // 4096

typedef __attribute__((ext_vector_type(8))) short short8;   // 8 bf16 (16x16x32 A/B frag)
typedef __attribute__((ext_vector_type(4))) short short4v;  // 4 bf16 (16x16x16 A/B frag)
typedef __attribute__((ext_vector_type(4))) float floatx4;  // MFMA C/D frag

// global -> LDS direct (16B per lane; LDS dst is wave-uniform base, +lane*16 implicit)
#define GL2LDS(gsrc, ldst) __builtin_amdgcn_global_load_lds( \
    (const __attribute__((address_space(1))) void*)(gsrc), \
    (__attribute__((address_space(3))) void*)(ldst), 16, 0, 0)

__device__ __forceinline__ short f2bf(float f) {
  union { float f; unsigned u; } v; v.f = f;
  unsigned u = v.u;
  unsigned r = (u + 0x7fffu + ((u >> 16) & 1u)) >> 16;  // RNE
  return (short)r;
}

// One fused fp32->bf16 cast for x (1048576 vec4), qkv_w (786432), out_w (262144)
__global__ __launch_bounds__(256) void cvt3_f32_bf16(
    const float* __restrict__ a, const float* __restrict__ b, const float* __restrict__ c,
    short* __restrict__ oa, short* __restrict__ ob, short* __restrict__ oc) {
  int i = blockIdx.x * 256 + threadIdx.x;
  const float* src; short* dst; int j;
  if (i < 1048576)      { src = a; dst = oa; j = i; }
  else if (i < 1835008) { src = b; dst = ob; j = i - 1048576; }
  else                  { src = c; dst = oc; j = i - 1835008; }
  float4 f = reinterpret_cast<const float4*>(src)[j];
  short4 o;
  o.x = f2bf(f.x); o.y = f2bf(f.y); o.z = f2bf(f.z); o.w = f2bf(f.w);
  reinterpret_cast<short4*>(dst)[j] = o;
}

// ---------------------------------------------------------------------------
// QKV projection: C[4096,3072] = A[4096,1024] @ B[3072,1024]^T, bf16 in, fp32 acc.
// 256x256 tile, BK=64, 512 threads (8 waves in 2x4; each wave owns 128x64 output).
// Double-buffered LDS (128 KiB), prefetch distance = 1 K-tile:
//   stage(t+1) is issued immediately AFTER the boundary __syncthreads() of tile t,
//   so the next boundary's vmcnt(0) drain hits loads that are ~4 MFMA-phases old
//   (drain is free, unlike the single-buffered stage->sync->compute structure).
// Intra-tile: NO barriers (LDS read-only) -> compiler pipelines ds_read vs MFMA
// with counted lgkmcnt. setprio(1) around each 16-MFMA cluster (T5).
// Epilogue: qkv scatter (q scaled by hd^-0.5*log2e, k row-major, v transposed).
// ---------------------------------------------------------------------------
__device__ __forceinline__ void stage256(const short* __restrict__ A, const short* __restrict__ B,
                                         int row0, int col0, int k0,
                                         short* Asb, short* Bsb, int tid, int wv) {
#pragma unroll
  for (int ld = 0; ld < 4; ++ld) {
    int chunk = ld * 512 + tid;                       // 0..2047 (16B chunks of 256x64 tile)
    int r = chunk >> 3;                               // row 0..255
    int c = ((chunk & 7) ^ (r & 7)) << 3;             // XOR-swizzled source col (shorts)
    GL2LDS(A + (long)(row0 + r) * 1024 + k0 + c, Asb + (ld * 512 + wv * 64) * 8);
    GL2LDS(B + (long)(col0 + r) * 1024 + k0 + c, Bsb + (ld * 512 + wv * 64) * 8);
  }
}

__global__ __launch_bounds__(512, 2) void gemm_qkv256(
    const short* __restrict__ A, const short* __restrict__ B,
    short* __restrict__ outQ, short* __restrict__ outK, short* __restrict__ outV)
{
  __shared__ __align__(16) short As[2][256 * 64];   // 64 KiB
  __shared__ __align__(16) short Bs[2][256 * 64];   // 64 KiB
  const int tid = threadIdx.x;
  const int wv = tid >> 6, lane = tid & 63;
  const int l15 = lane & 15, quad = lane >> 4;
  const int swl = l15 & 7;
  const int wr = wv >> 2, wc = wv & 3;              // 2x4 wave grid
  const int row0 = blockIdx.y * 256, col0 = blockIdx.x * 256;

  floatx4 acc[8][4];
#pragma unroll
  for (int i = 0; i < 8; i++)
#pragma unroll
    for (int j = 0; j < 4; j++) acc[i][j] = (floatx4){0.f, 0.f, 0.f, 0.f};

  int buf = 0;
  stage256(A, B, row0, col0, 0, As[0], Bs[0], tid, wv);

  for (int t = 0; t < 16; ++t) {
    __syncthreads();                 // vmcnt(0)+barrier: tile t staged (4 phases old), t-1 reads done
    if (t + 1 < 16)                  // prefetch t+1 into buf^1 (its old contents consumed pre-barrier)
      stage256(A, B, row0, col0, (t + 1) * 64, As[buf ^ 1], Bs[buf ^ 1], tid, wv);

    const short* Ab = As[buf];
    const short* Bb = Bs[buf];
#pragma unroll
    for (int kk = 0; kk < 2; ++kk) {
      short8 bfr[4];
#pragma unroll
      for (int ni = 0; ni < 4; ++ni)
        bfr[ni] = *(const short8*)(Bb + (wc * 64 + ni * 16 + l15) * 64 + (((kk * 4 + quad) ^ swl) << 3));
#pragma unroll
      for (int mh = 0; mh < 2; ++mh) {
        short8 af[4];
#pragma unroll
        for (int a = 0; a < 4; ++a)
          af[a] = *(const short8*)(Ab + (wr * 128 + mh * 64 + a * 16 + l15) * 64 + (((kk * 4 + quad) ^ swl) << 3));
        __builtin_amdgcn_s_setprio(1);
#pragma unroll
        for (int a = 0; a < 4; ++a)
#pragma unroll
          for (int ni = 0; ni < 4; ++ni)
            acc[mh * 4 + a][ni] = __builtin_amdgcn_mfma_f32_16x16x32_bf16(af[a], bfr[ni], acc[mh * 4 + a][ni], 0, 0, 0);
        __builtin_amdgcn_s_setprio(0);
      }
    }
    buf ^= 1;
  }

  // qkv scatter epilogue: j = t*1024 + h*64 + d ; i = b*2048 + s
#pragma unroll
  for (int mi = 0; mi < 8; ++mi) {
    int rowg = row0 + wr * 128 + mi * 16 + quad * 4;
#pragma unroll
    for (int ni = 0; ni < 4; ++ni) {
      int j = col0 + wc * 64 + ni * 16 + l15;
      int tt = j >> 10;
      int rem = j & 1023;
      int h = rem >> 6, d = rem & 63;
#pragma unroll
      for (int r = 0; r < 4; ++r) {
        int i = rowg + r;
        int b = i >> 11, s = i & 2047;
        int bh = b * HEADS + h;
        float v = acc[mi][ni][r];
        // q scale = hd^-0.5 * log2(e) so flash can use raw v_exp_f32 (2^x)
        if (tt == 0)      outQ[(bh * SEQ + s) * HDIM + d] = f2bf(v * 0.18033688011112042f);
        else if (tt == 1) outK[(bh * SEQ + s) * HDIM + d] = f2bf(v);
        else              outV[(bh * HDIM + d) * SEQ + s] = f2bf(v);          // transposed
      }
    }
  }
}

// C[M,N] = A[M,K] @ B[N,K]^T, bf16 in, fp32 accum.  (used for output projection)
// 128xBN tile, BK=64 (XOR-swizzled LDS rows of 128B keep b128 reads bank-minimal),
// 4 waves in 2x2, each wave 64x(BN/2). EPI==2: plain fp32 C row-major.
template<int EPI, int BN>
__global__ __launch_bounds__(256) void gemm_bt(
    const short* __restrict__ A, const short* __restrict__ B,
    int M, int N, int K,
    float* __restrict__ outF,
    short* __restrict__ outQ, short* __restrict__ outK, short* __restrict__ outV)
{
  constexpr int WN = BN / 2;   // wave col extent
  constexpr int NI = BN / 32;  // 16-col tiles per wave
  __shared__ __align__(16) short As[128*64];
  __shared__ __align__(16) short Bs[BN*64];
  const int tid = threadIdx.x;
  const int wv = tid >> 6;
  const int lane = tid & 63;
  const int l15 = lane & 15;
  const int quad = lane >> 4;
  const int swl = l15 & 7;
  const int wm = wv >> 1, wn = wv & 1;
  const int row0 = blockIdx.y * 128, col0 = blockIdx.x * BN;

  floatx4 acc[4][NI];
#pragma unroll
  for (int i = 0; i < 4; i++)
#pragma unroll
    for (int j = 0; j < NI; j++) acc[i][j] = (floatx4){0.f, 0.f, 0.f, 0.f};

  for (int k0 = 0; k0 < K; k0 += 64) {
#pragma unroll
    for (int rd = 0; rd < 4; ++rd) {
      int chunk = rd * 256 + tid;
      int r = chunk >> 3, c = ((chunk & 7) ^ (r & 7)) << 3;
      GL2LDS(A + (long)(row0 + r) * K + k0 + c, As + (rd * 256 + wv * 64) * 8);
    }
#pragma unroll
    for (int rd = 0; rd < BN / 32; ++rd) {
      int chunk = rd * 256 + tid;
      int r = chunk >> 3, c = ((chunk & 7) ^ (r & 7)) << 3;
      GL2LDS(B + (long)(col0 + r) * K + k0 + c, Bs + (rd * 256 + wv * 64) * 8);
    }
    __syncthreads();

    short8 af[4][2], bfr[NI][2];
#pragma unroll
    for (int mi = 0; mi < 4; mi++) {
      const short* ap = As + (wm * 64 + mi * 16 + l15) * 64;
#pragma unroll
      for (int kk = 0; kk < 2; kk++)
        af[mi][kk] = *(const short8*)(ap + (((kk * 4 + quad) ^ swl) << 3));
    }
#pragma unroll
    for (int ni = 0; ni < NI; ni++) {
      const short* bp = Bs + (wn * WN + ni * 16 + l15) * 64;
#pragma unroll
      for (int kk = 0; kk < 2; kk++)
        bfr[ni][kk] = *(const short8*)(bp + (((kk * 4 + quad) ^ swl) << 3));
    }
#pragma unroll
    for (int mi = 0; mi < 4; mi++)
#pragma unroll
      for (int ni = 0; ni < NI; ni++)
#pragma unroll
        for (int kk = 0; kk < 2; kk++)
          acc[mi][ni] = __builtin_amdgcn_mfma_f32_16x16x32_bf16(af[mi][kk], bfr[ni][kk], acc[mi][ni], 0, 0, 0);
    __syncthreads();
  }

  if (EPI == 2) {
#pragma unroll
    for (int mi = 0; mi < 4; mi++) {
      int rr = row0 + wm * 64 + mi * 16 + quad * 4;
#pragma unroll
      for (int ni = 0; ni < NI; ni++) {
        int cc = col0 + wn * WN + ni * 16 + l15;
#pragma unroll
        for (int r = 0; r < 4; r++)
          outF[(long)(rr + r) * N + cc] = acc[mi][ni][r];
      }
    }
  }
}

// K/V tile staging for 256-thread blocks: 64x64 K and 64x64 V^T, XOR-swizzled 16B chunks.
__device__ __forceinline__ void stage_kv(const short* __restrict__ kg,
                                         const short* __restrict__ vT,
                                         int bh, int kt, short* KsB, short* VsB,
                                         int tid, int wv) {
#pragma unroll
  for (int i = 0; i < 2; ++i) {
    int slot = i * 256 + tid;                 // 0..511
    int r = slot >> 3;
    int c = ((slot & 7) ^ (r & 7)) << 3;
    GL2LDS(kg + (bh * SEQ + kt * 64 + r) * HDIM + c, KsB + (i * 256 + wv * 64) * 8);
    GL2LDS(vT + (bh * HDIM + r) * SEQ + kt * 64 + c, VsB + (i * 256 + wv * 64) * 8);
  }
}

// Flash attention v8: 64-row blocks, 4 waves x 16 q-rows each (v7 structure)
//  + T5 setprio(1) around both MFMA clusters (catalog: attn +4-7%).
__global__ __launch_bounds__(256, 4) void flash_attn(
    const short* __restrict__ qg, const short* __restrict__ kg,
    const short* __restrict__ vT, short* __restrict__ attn)
{
  __shared__ __align__(16) short Ks[2][64 * 64];
  __shared__ __align__(16) short Vs[2][64 * 64];

  const int tid = threadIdx.x;
  const int wv = tid >> 6, lane = tid & 63;
  const int l15 = lane & 15, quad = lane >> 4;
  const int bh = blockIdx.x;
  // balanced work mapping (bijective on 0..31): sgrp 0..3 -> {y0, 15-y0, 16+y0, 31-y0}
  const int yl = (int)blockIdx.y;
  const int sgrp = yl >> 3, y0 = yl & 7;
  const int yp = ((sgrp >> 1) << 4) + ((sgrp & 1) ? (15 - y0) : y0);
  const int rt = 31 - yp;                   // q row-tile (64 rows); ntiles = rt+1
  const int m0 = rt * 64 + wv * 16;         // wave's first q row
  const int swl = l15 & 7;

  // Q frags (persistent): B-operand for S^T: n=q=m0+l15, k=d=kk*32+quad*8+j
  short8 aq[2];
  {
    const short* qp = qg + (long)(bh * SEQ + m0 + l15) * HDIM + quad * 8;
    aq[0] = *(const short8*)qp;
    aq[1] = *(const short8*)(qp + 32);
  }

  const short ONE = (short)0x3F80;  // bf16 1.0
  const short4v ones4 = {ONE, ONE, ONE, ONE};

  floatx4 o[4], lsum = (floatx4){0.f, 0.f, 0.f, 0.f};
#pragma unroll
  for (int nt = 0; nt < 4; nt++) o[nt] = (floatx4){0.f, 0.f, 0.f, 0.f};

  const int ntiles = rt + 1;
  stage_kv(kg, vT, bh, 0, Ks[0], Vs[0], tid, wv);

  for (int kt = 0; kt < ntiles; ++kt) {
    __syncthreads();                         // drains GL2LDS (vmcnt 0) + syncs: buf[kt&1] ready
    const int buf = kt & 1;
    if (kt + 1 < ntiles)                     // prefetch next tile; drained at NEXT barrier
      stage_kv(kg, vT, bh, kt + 1, Ks[buf ^ 1], Vs[buf ^ 1], tid, wv);

    const short* KsB = Ks[buf];
    const short* VsB = Vs[buf];

    // ---- S^T = K . Q^T (16x16x32): D[row=kpos(quad*4+r)][col=q(l15)] ----
    floatx4 sc4[4];
#pragma unroll
    for (int nh = 0; nh < 4; nh++) sc4[nh] = (floatx4){0.f, 0.f, 0.f, 0.f};
    __builtin_amdgcn_s_setprio(1);
#pragma unroll
    for (int nh = 0; nh < 4; nh++) {
      const short* kp = KsB + (nh * 16 + l15) * 64;
      short8 kf0 = *(const short8*)(kp + ((quad ^ swl) << 3));         // A: m=kpos, k=d 0..31
      short8 kf1 = *(const short8*)(kp + (((4 + quad) ^ swl) << 3));   // k=d 32..63
      sc4[nh] = __builtin_amdgcn_mfma_f32_16x16x32_bf16(kf0, aq[0], sc4[nh], 0, 0, 0);
      sc4[nh] = __builtin_amdgcn_mfma_f32_16x16x32_bf16(kf1, aq[1], sc4[nh], 0, 0, 0);
    }
    __builtin_amdgcn_s_setprio(0);

    // ---- softmax (static max, exp2 domain) + pack P into K=16 A-frags (registers) ----
    short4v pa[4];
    const int qrow = m0 + l15;
    const bool full = (kt * 64 + 63) <= m0;  // wave-uniform
#pragma unroll
    for (int nh = 0; nh < 4; nh++) {
      unsigned u[4];
#pragma unroll
      for (int r = 0; r < 4; r++) {
        float pe = __builtin_amdgcn_exp2f(sc4[nh][r]);
        if (!full) {
          const int kpos = kt * 64 + nh * 16 + quad * 4 + r;
          pe = (kpos <= qrow) ? pe : 0.f;
        }
        u[r] = __builtin_bit_cast(unsigned, pe) & 0xffff0000u;  // trunc to bf16
      }
      uint2 w;
      w.x = (u[0] >> 16) | u[1];   // k = quad*4 + {0,1}
      w.y = (u[2] >> 16) | u[3];   // k = quad*4 + {2,3}
      pa[nh] = __builtin_bit_cast(short4v, w);
    }

    // ---- P @ V and P @ ones via 16x16x16 MFMA (P direct from registers) ----
    __builtin_amdgcn_s_setprio(1);
#pragma unroll
    for (int kk = 0; kk < 4; kk++) {
      short4v bv[4];
#pragma unroll
      for (int nt = 0; nt < 4; nt++) {
        const int ch = (kk * 2 + (quad >> 1)) ^ swl;   // 16B-chunk swizzle
        bv[nt] = *(const short4v*)(VsB + (nt * 16 + l15) * 64 + (ch << 3) + ((quad & 1) << 2));
      }
      lsum = __builtin_amdgcn_mfma_f32_16x16x16bf16_1k(pa[kk], ones4, lsum, 0, 0, 0);
#pragma unroll
      for (int nt = 0; nt < 4; nt++)
        o[nt] = __builtin_amdgcn_mfma_f32_16x16x16bf16_1k(pa[kk], bv[nt], o[nt], 0, 0, 0);
    }
    __builtin_amdgcn_s_setprio(0);
  }

  const int b = bh >> 4, h = bh & 15;
#pragma unroll
  for (int r = 0; r < 4; r++) {
    const float inv = 1.0f / lsum[r];
    const int srow = m0 + quad * 4 + r;
#pragma unroll
    for (int nt = 0; nt < 4; nt++)
      attn[(long)(b * SEQ + srow) * HIDDEN + h * HDIM + nt * 16 + l15] = f2bf(o[nt][r] * inv);
  }
}

extern "C" void kernel_launch(void* const* d_in, const int* in_sizes, int n_in,
                              void* d_out, int out_size, void* d_ws, size_t ws_size,
                              hipStream_t stream) {
  const float* x     = (const float*)d_in[0];  // [2,2048,1024]
  const float* qkv_w = (const float*)d_in[1];  // [3072,1024]
  const float* out_w = (const float*)d_in[2];  // [1024,1024]
  float* out = (float*)d_out;                  // [2,2048,1024] fp32

  short* xb   = (short*)d_ws;                       // 4096*1024
  short* wqb  = xb  + MTOT * HIDDEN;                // 3072*1024
  short* wob  = wqb + 3 * HIDDEN * HIDDEN;          // 1024*1024
  short* qB   = wob + HIDDEN * HIDDEN;              // 32*2048*64
  short* kB   = qB  + BHN * SEQ * HDIM;
  short* vTB  = kB  + BHN * SEQ * HDIM;
  short* attn = vTB + BHN * SEQ * HDIM;             // 4096*1024

  // fused bf16 casts: (4096+3072+1024)*1024/4 = 2097152 vec4 -> 8192 blocks
  cvt3_f32_bf16<<<dim3(8192), dim3(256), 0, stream>>>(x, qkv_w, out_w, xb, wqb, wob);

  // QKV projection: M=4096, N=3072, K=1024 — 256^2 tile, 512 thr, dbuf prefetch-1
  gemm_qkv256<<<dim3(3 * HIDDEN / 256, MTOT / 256), dim3(512), 0, stream>>>(
      xb, wqb, qB, kB, vTB);

  // causal attention: 64-row 4-wave blocks, balanced per-CU work mapping
  flash_attn<<<dim3(BHN, SEQ / 64), dim3(256), 0, stream>>>(qB, kB, vTB, attn);

  // output projection: M=4096, N=1024, K=1024 (128x64 tiles -> 512 blocks), BK=64
  gemm_bt<2, 64><<<dim3(HIDDEN / 64, MTOT / 128), dim3(256), 0, stream>>>(
      attn, wob, MTOT, HIDDEN, HIDDEN, out, nullptr, nullptr, nullptr);
}

// Round 3
// 173.626 us; speedup vs baseline: 1.1638x; 1.1638x over previous
//
#include <hip/hip_runtime.h>
#include <hip/hip_bf16.h>
#include <math.h>

// Problem constants (CPUEfficientCausalAttention): B=2, S=2048, HIDDEN=1024, H=16, hd=64
#define HIDDEN 1024
#define HEADS 16
#define HDIM 64
#define BATCH 2
#define SEQ 2048
#define BHN (BATCH*HEADS)   // 32
#define MTOT (BATCH*SEQ)    // 4096

typedef __attribute__((ext_vector_type(8))) short short8;   // 8 bf16 (16x16x32 A/B frag)
typedef __attribute__((ext_vector_type(4))) short short4v;  // 4 bf16 (16x16x16 A/B frag)
typedef __attribute__((ext_vector_type(4))) float floatx4;  // MFMA C/D frag

// global -> LDS direct (16B per lane; LDS dst is wave-uniform base, +lane*16 implicit)
#define GL2LDS(gsrc, ldst) __builtin_amdgcn_global_load_lds( \
    (const __attribute__((address_space(1))) void*)(gsrc), \
    (__attribute__((address_space(3))) void*)(ldst), 16, 0, 0)

__device__ __forceinline__ short f2bf(float f) {
  union { float f; unsigned u; } v; v.f = f;
  unsigned u = v.u;
  unsigned r = (u + 0x7fffu + ((u >> 16) & 1u)) >> 16;  // RNE
  return (short)r;
}

// One fused fp32->bf16 cast for x (1048576 vec4), qkv_w (786432), out_w (262144)
__global__ __launch_bounds__(256) void cvt3_f32_bf16(
    const float* __restrict__ a, const float* __restrict__ b, const float* __restrict__ c,
    short* __restrict__ oa, short* __restrict__ ob, short* __restrict__ oc) {
  int i = blockIdx.x * 256 + threadIdx.x;
  const float* src; short* dst; int j;
  if (i < 1048576)      { src = a; dst = oa; j = i; }
  else if (i < 1835008) { src = b; dst = ob; j = i - 1048576; }
  else                  { src = c; dst = oc; j = i - 1835008; }
  float4 f = reinterpret_cast<const float4*>(src)[j];
  short4 o;
  o.x = f2bf(f.x); o.y = f2bf(f.y); o.z = f2bf(f.z); o.w = f2bf(f.w);
  reinterpret_cast<short4*>(dst)[j] = o;
}

// C[M,N] = A[M,K] @ B[N,K]^T, bf16 in, fp32 accum.  (PROVEN structure, 42.4us QKV)
// 128xBN tile, BK=64 (XOR-swizzled LDS rows of 128B keep b128 reads bank-minimal),
// 4 waves in 2x2, each wave 64x(BN/2).
// EPI==1 (BN=128): scatter qkv epilogue (q scaled by hd^-0.5*log2e, k row-major, v transposed)
// EPI==2: plain fp32 C row-major
template<int EPI, int BN>
__global__ __launch_bounds__(256) void gemm_bt(
    const short* __restrict__ A, const short* __restrict__ B,
    int M, int N, int K,
    float* __restrict__ outF,
    short* __restrict__ outQ, short* __restrict__ outK, short* __restrict__ outV)
{
  constexpr int WN = BN / 2;   // wave col extent
  constexpr int NI = BN / 32;  // 16-col tiles per wave
  __shared__ __align__(16) short As[128*64];
  __shared__ __align__(16) short Bs[BN*64];
  const int tid = threadIdx.x;
  const int wv = tid >> 6;
  const int lane = tid & 63;
  const int l15 = lane & 15;
  const int quad = lane >> 4;
  const int swl = l15 & 7;
  const int wm = wv >> 1, wn = wv & 1;
  const int row0 = blockIdx.y * 128, col0 = blockIdx.x * BN;

  floatx4 acc[4][NI];
#pragma unroll
  for (int i = 0; i < 4; i++)
#pragma unroll
    for (int j = 0; j < NI; j++) acc[i][j] = (floatx4){0.f, 0.f, 0.f, 0.f};

  for (int k0 = 0; k0 < K; k0 += 64) {
    // stage A [128][64] (1024 16B-chunks) and B [BN][64], XOR-swizzled on source col
#pragma unroll
    for (int rd = 0; rd < 4; ++rd) {
      int chunk = rd * 256 + tid;
      int r = chunk >> 3, c = ((chunk & 7) ^ (r & 7)) << 3;
      GL2LDS(A + (long)(row0 + r) * K + k0 + c, As + (rd * 256 + wv * 64) * 8);
    }
#pragma unroll
    for (int rd = 0; rd < BN / 32; ++rd) {
      int chunk = rd * 256 + tid;
      int r = chunk >> 3, c = ((chunk & 7) ^ (r & 7)) << 3;
      GL2LDS(B + (long)(col0 + r) * K + k0 + c, Bs + (rd * 256 + wv * 64) * 8);
    }
    __syncthreads();

    short8 af[4][2], bfr[NI][2];
#pragma unroll
    for (int mi = 0; mi < 4; mi++) {
      const short* ap = As + (wm * 64 + mi * 16 + l15) * 64;
#pragma unroll
      for (int kk = 0; kk < 2; kk++)
        af[mi][kk] = *(const short8*)(ap + (((kk * 4 + quad) ^ swl) << 3));
    }
#pragma unroll
    for (int ni = 0; ni < NI; ni++) {
      const short* bp = Bs + (wn * WN + ni * 16 + l15) * 64;
#pragma unroll
      for (int kk = 0; kk < 2; kk++)
        bfr[ni][kk] = *(const short8*)(bp + (((kk * 4 + quad) ^ swl) << 3));
    }
#pragma unroll
    for (int mi = 0; mi < 4; mi++)
#pragma unroll
      for (int ni = 0; ni < NI; ni++)
#pragma unroll
        for (int kk = 0; kk < 2; kk++)
          acc[mi][ni] = __builtin_amdgcn_mfma_f32_16x16x32_bf16(af[mi][kk], bfr[ni][kk], acc[mi][ni], 0, 0, 0);
    __syncthreads();
  }

  if (EPI == 2) {
#pragma unroll
    for (int mi = 0; mi < 4; mi++) {
      int rr = row0 + wm * 64 + mi * 16 + quad * 4;
#pragma unroll
      for (int ni = 0; ni < NI; ni++) {
        int cc = col0 + wn * WN + ni * 16 + l15;
#pragma unroll
        for (int r = 0; r < 4; r++)
          outF[(long)(rr + r) * N + cc] = acc[mi][ni][r];
      }
    }
  } else {
    // qkv scatter: j = t*1024 + h*64 + d ; i = b*2048 + s
#pragma unroll
    for (int mi = 0; mi < 4; mi++) {
      int rowg = row0 + wm * 64 + mi * 16 + quad * 4;
#pragma unroll
      for (int ni = 0; ni < NI; ni++) {
        int j = col0 + wn * WN + ni * 16 + l15;
        int t = j >> 10;
        int rem = j & 1023;
        int h = rem >> 6, d = rem & 63;
#pragma unroll
        for (int r = 0; r < 4; r++) {
          int i = rowg + r;
          int b = i >> 11, s = i & 2047;
          int bh = b * HEADS + h;
          float v = acc[mi][ni][r];
          // q scale = hd^-0.5 * log2(e) so flash can use raw v_exp_f32 (2^x)
          if (t == 0)      outQ[(bh * SEQ + s) * HDIM + d] = f2bf(v * 0.18033688011112042f);
          else if (t == 1) outK[(bh * SEQ + s) * HDIM + d] = f2bf(v);
          else             outV[(bh * HDIM + d) * SEQ + s] = f2bf(v);          // transposed
        }
      }
    }
  }
}

// K/V tile staging for 256-thread blocks: 64x64 K and 64x64 V^T, XOR-swizzled 16B chunks.
__device__ __forceinline__ void stage_kv(const short* __restrict__ kg,
                                         const short* __restrict__ vT,
                                         int bh, int kt, short* KsB, short* VsB,
                                         int tid, int wv) {
#pragma unroll
  for (int i = 0; i < 2; ++i) {
    int slot = i * 256 + tid;                 // 0..511
    int r = slot >> 3;
    int c = ((slot & 7) ^ (r & 7)) << 3;
    GL2LDS(kg + (bh * SEQ + kt * 64 + r) * HDIM + c, KsB + (i * 256 + wv * 64) * 8);
    GL2LDS(vT + (bh * HDIM + r) * SEQ + kt * 64 + c, VsB + (i * 256 + wv * 64) * 8);
  }
}

// Flash attention v9: 64-row blocks, 4 waves in a 2x2 (q-half x kpos-half) split.
//  - wave (qh,kh): qh picks 32 q-rows, kh picks 32 of the 64 key positions per tile.
//    Each wave reads only HALF the K and V tile from LDS (4KB+4KB vs v7's 8+8)
//    -> block LDS traffic per tile halves; MFMA / exp2 per wave unchanged.
//  - static-max softmax (exp2 domain) makes the two kpos-half partials (o, lsum)
//    directly ADDITIVE: one LDS merge at the end (o -> Ks scratch, lsum -> Vs).
//  - occupancy unchanged: 32KB LDS, 1024 blocks, 4 blk/CU x 4 waves = 4 waves/SIMD.
//  - balanced y-remap + dbuf GL2LDS staging + setprio, as in v7/v8.
__global__ __launch_bounds__(256, 4) void flash_attn(
    const short* __restrict__ qg, const short* __restrict__ kg,
    const short* __restrict__ vT, short* __restrict__ attn)
{
  __shared__ __align__(16) short Ks[2][64 * 64];
  __shared__ __align__(16) short Vs[2][64 * 64];

  const int tid = threadIdx.x;
  const int wv = tid >> 6, lane = tid & 63;
  const int l15 = lane & 15, quad = lane >> 4;
  const int bh = blockIdx.x;
  // balanced work mapping (bijective on 0..31): sgrp 0..3 -> {y0, 15-y0, 16+y0, 31-y0}
  const int yl = (int)blockIdx.y;
  const int sgrp = yl >> 3, y0 = yl & 7;
  const int yp = ((sgrp >> 1) << 4) + ((sgrp & 1) ? (15 - y0) : y0);
  const int rt = 31 - yp;                   // q row-tile (64 rows); ntiles = rt+1
  const int qh = wv >> 1;                   // q-half: 32 rows
  const int kh = wv & 1;                    // kpos-half: 32 positions per tile
  const int m0 = rt * 64 + qh * 32;         // wave's first q row
  const int swl = l15 & 7;

  // Q frags (persistent): B-operand for S^T: n=q=m0+g*16+l15, k=d=kk*32+quad*8+j
  short8 aq[2][2];
#pragma unroll
  for (int g = 0; g < 2; g++) {
    const short* qp = qg + (long)(bh * SEQ + m0 + g * 16 + l15) * HDIM + quad * 8;
    aq[g][0] = *(const short8*)qp;
    aq[g][1] = *(const short8*)(qp + 32);
  }

  const short ONE = (short)0x3F80;  // bf16 1.0
  const short4v ones4 = {ONE, ONE, ONE, ONE};

  floatx4 o[2][4], lsum[2];
#pragma unroll
  for (int g = 0; g < 2; g++) {
    lsum[g] = (floatx4){0.f, 0.f, 0.f, 0.f};
#pragma unroll
    for (int nt = 0; nt < 4; nt++) o[g][nt] = (floatx4){0.f, 0.f, 0.f, 0.f};
  }

  const int ntiles = rt + 1;
  stage_kv(kg, vT, bh, 0, Ks[0], Vs[0], tid, wv);

  for (int kt = 0; kt < ntiles; ++kt) {
    __syncthreads();                         // drains GL2LDS (vmcnt 0) + syncs: buf[kt&1] ready
    const int buf = kt & 1;
    if (kt + 1 < ntiles)                     // prefetch next tile; drained at NEXT barrier
      stage_kv(kg, vT, bh, kt + 1, Ks[buf ^ 1], Vs[buf ^ 1], tid, wv);

    const short* KsB = Ks[buf];
    const short* VsB = Vs[buf];

    // ---- S^T quarter = K[kh-half] . Q[qh-half]^T (16x16x32) ----
    // D[row=kpos(quad*4+r) within sub][col=q(l15)]
    floatx4 sc[2][2];                        // [g][sub]
#pragma unroll
    for (int g = 0; g < 2; g++)
#pragma unroll
      for (int sub = 0; sub < 2; sub++) sc[g][sub] = (floatx4){0.f, 0.f, 0.f, 0.f};
    __builtin_amdgcn_s_setprio(1);
#pragma unroll
    for (int sub = 0; sub < 2; sub++) {
      const short* kp = KsB + (kh * 32 + sub * 16 + l15) * 64;
      short8 kf0 = *(const short8*)(kp + ((quad ^ swl) << 3));         // A: m=kpos, k=d 0..31
      short8 kf1 = *(const short8*)(kp + (((4 + quad) ^ swl) << 3));   // k=d 32..63
#pragma unroll
      for (int g = 0; g < 2; g++) {
        sc[g][sub] = __builtin_amdgcn_mfma_f32_16x16x32_bf16(kf0, aq[g][0], sc[g][sub], 0, 0, 0);
        sc[g][sub] = __builtin_amdgcn_mfma_f32_16x16x32_bf16(kf1, aq[g][1], sc[g][sub], 0, 0, 0);
      }
    }
    __builtin_amdgcn_s_setprio(0);

    // ---- softmax (static max, exp2 domain) + pack P into K=16 A-frags (registers) ----
    short4v pa[2][2];
#pragma unroll
    for (int g = 0; g < 2; g++) {
      const int qrow = m0 + g * 16 + l15;
#pragma unroll
      for (int sub = 0; sub < 2; sub++) {
        const int kbase = kt * 64 + kh * 32 + sub * 16;
        const bool full = (kbase + 15) <= (m0 + g * 16);  // wave-uniform per (g,sub)
        unsigned u[4];
#pragma unroll
        for (int r = 0; r < 4; r++) {
          float pe = __builtin_amdgcn_exp2f(sc[g][sub][r]);
          if (!full) {
            const int kpos = kbase + quad * 4 + r;
            pe = (kpos <= qrow) ? pe : 0.f;
          }
          u[r] = __builtin_bit_cast(unsigned, pe) & 0xffff0000u;  // trunc to bf16
        }
        uint2 w;
        w.x = (u[0] >> 16) | u[1];   // k = quad*4 + {0,1}
        w.y = (u[2] >> 16) | u[3];   // k = quad*4 + {2,3}
        pa[g][sub] = __builtin_bit_cast(short4v, w);
      }
    }

    // ---- partial P @ V and P @ ones via 16x16x16 MFMA (k-dim = wave's kpos-half) ----
    __builtin_amdgcn_s_setprio(1);
#pragma unroll
    for (int sub = 0; sub < 2; sub++) {
      short4v bv[4];
#pragma unroll
      for (int nt = 0; nt < 4; nt++) {
        const int ch = (kh * 4 + sub * 2 + (quad >> 1)) ^ swl;   // 16B-chunk swizzle
        bv[nt] = *(const short4v*)(VsB + (nt * 16 + l15) * 64 + (ch << 3) + ((quad & 1) << 2));
      }
#pragma unroll
      for (int g = 0; g < 2; g++) {
        lsum[g] = __builtin_amdgcn_mfma_f32_16x16x16bf16_1k(pa[g][sub], ones4, lsum[g], 0, 0, 0);
#pragma unroll
        for (int nt = 0; nt < 4; nt++)
          o[g][nt] = __builtin_amdgcn_mfma_f32_16x16x16bf16_1k(pa[g][sub], bv[nt], o[g][nt], 0, 0, 0);
      }
    }
    __builtin_amdgcn_s_setprio(0);
  }

  // ---- merge kpos-half partials: kh=1 writes to LDS scratch, kh=0 adds ----
  __syncthreads();                         // all compute done; Ks/Vs reusable as scratch
  float* redO = (float*)&Ks[0][0];         // 2 waves x 64 lanes x 2 g x 16 = 4096 floats (16KB)
  float* redL = (float*)&Vs[0][0];         // 2 waves x 64 lanes x 2 g x 4  = 1024 floats
  if (kh == 1) {
#pragma unroll
    for (int g = 0; g < 2; g++) {
      const int base = (qh * 64 + lane) * 2 + g;
#pragma unroll
      for (int nt = 0; nt < 4; nt++)
#pragma unroll
        for (int r = 0; r < 4; r++)
          redO[base * 16 + nt * 4 + r] = o[g][nt][r];
#pragma unroll
      for (int r = 0; r < 4; r++) redL[base * 4 + r] = lsum[g][r];
    }
  }
  __syncthreads();
  if (kh == 0) {
    const int b = bh >> 4, h = bh & 15;
#pragma unroll
    for (int g = 0; g < 2; g++) {
      const int base = (qh * 64 + lane) * 2 + g;
      floatx4 lt = lsum[g];
#pragma unroll
      for (int r = 0; r < 4; r++) lt[r] += redL[base * 4 + r];
#pragma unroll
      for (int r = 0; r < 4; r++) {
        const float inv = 1.0f / lt[r];
        const int srow = m0 + g * 16 + quad * 4 + r;
#pragma unroll
        for (int nt = 0; nt < 4; nt++) {
          float val = o[g][nt][r] + redO[base * 16 + nt * 4 + r];
          attn[(long)(b * SEQ + srow) * HIDDEN + h * HDIM + nt * 16 + l15] = f2bf(val * inv);
        }
      }
    }
  }
}

extern "C" void kernel_launch(void* const* d_in, const int* in_sizes, int n_in,
                              void* d_out, int out_size, void* d_ws, size_t ws_size,
                              hipStream_t stream) {
  const float* x     = (const float*)d_in[0];  // [2,2048,1024]
  const float* qkv_w = (const float*)d_in[1];  // [3072,1024]
  const float* out_w = (const float*)d_in[2];  // [1024,1024]
  float* out = (float*)d_out;                  // [2,2048,1024] fp32

  short* xb   = (short*)d_ws;                       // 4096*1024
  short* wqb  = xb  + MTOT * HIDDEN;                // 3072*1024
  short* wob  = wqb + 3 * HIDDEN * HIDDEN;          // 1024*1024
  short* qB   = wob + HIDDEN * HIDDEN;              // 32*2048*64
  short* kB   = qB  + BHN * SEQ * HDIM;
  short* vTB  = kB  + BHN * SEQ * HDIM;
  short* attn = vTB + BHN * SEQ * HDIM;             // 4096*1024

  // fused bf16 casts: (4096+3072+1024)*1024/4 = 2097152 vec4 -> 8192 blocks
  cvt3_f32_bf16<<<dim3(8192), dim3(256), 0, stream>>>(x, qkv_w, out_w, xb, wqb, wob);

  // QKV projection: M=4096, N=3072, K=1024, BK=64 (proven 128x128 structure)
  gemm_bt<1, 128><<<dim3(3 * HIDDEN / 128, MTOT / 128), dim3(256), 0, stream>>>(
      xb, wqb, MTOT, 3 * HIDDEN, HIDDEN, nullptr, qB, kB, vTB);

  // causal attention: 64-row blocks, 2x2 (q-half x kpos-half) wave split
  flash_attn<<<dim3(BHN, SEQ / 64), dim3(256), 0, stream>>>(qB, kB, vTB, attn);

  // output projection: M=4096, N=1024, K=1024 (128x64 tiles -> 512 blocks), BK=64
  gemm_bt<2, 64><<<dim3(HIDDEN / 64, MTOT / 128), dim3(256), 0, stream>>>(
      attn, wob, MTOT, HIDDEN, HIDDEN, out, nullptr, nullptr, nullptr);
}